// Round 1
// baseline (345.985 us; speedup 1.0000x reference)
//
#include <hip/hip_runtime.h>
#include <hip/hip_bf16.h>

#define DI __device__ __forceinline__

typedef _Float16 half8 __attribute__((ext_vector_type(8)));
typedef float f32x4 __attribute__((ext_vector_type(4)));

constexpr int B_ = 16, H_ = 8, N_ = 300, U_ = 100, V_ = 200, HD_ = 16, E_ = 128, L_ = 3;
constexpr int EP = 208;              // padded logit columns (200 -> 208, multiple of 8)
constexpr float ALPHA_ = 0.01f;
constexpr float NEGI = -20000.0f;    // effective -inf: exp underflows to exactly 0 after max-sub

DI float leaky(float x) { return x > 0.f ? x : ALPHA_ * x; }
DI float elu_(float x)  { return x > 0.f ? x : __expf(x) - 1.f; }

DI unsigned short f2bf(float f) {   // RNE f32->bf16
  unsigned u = __float_as_uint(f);
  unsigned r = (u + 0x7FFFu + ((u >> 16) & 1u)) >> 16;
  return (unsigned short)r;
}
DI float ld_f(const void* p, long i, int isbf) {
  if (isbf) return __uint_as_float(((unsigned)((const unsigned short*)p)[i]) << 16);
  return ((const float*)p)[i];
}
DI bool adj_true(const void* a, long i, int k) {
  switch (k) {
    case 0:  return ((const int*)a)[i] != 0;
    case 1:  return ((const float*)a)[i] != 0.f;
    case 2:  return ((const unsigned short*)a)[i] != 0;
    default: return ((const unsigned char*)a)[i] != 0;
  }
}

// Runtime input-format detection (wave 0 scans leading bytes; writes flg[0]=float-is-bf16, flg[1]=adj kind)
DI void detect_flags(const void* x, const void* adj, int* flg) {
  if (threadIdx.x < 64) {
    int lane = threadIdx.x;
    const unsigned short* xh = (const unsigned short*)x;
    bool okbf = true;
    #pragma unroll
    for (int i = 0; i < 16; i++) {
      float f = __uint_as_float(((unsigned)xh[lane * 16 + i]) << 16);
      okbf = okbf && (f == f) && (fabsf(f) < 1e6f);   // f32 data has wild low-halfwords
    }
    int bfall = __all(okbf ? 1 : 0);
    int ak = 3;
    if (adj) {
      const unsigned* aw = (const unsigned*)adj;
      bool i32ok = true, f32ok = true, b16ok = true;
      #pragma unroll
      for (int i = 0; i < 16; i++) {
        unsigned w = aw[lane * 16 + i];
        i32ok = i32ok && (w == 0u || w == 1u);
        f32ok = f32ok && (w == 0u || w == 0x3F800000u);
        unsigned short h0 = (unsigned short)(w & 0xFFFFu), h1 = (unsigned short)(w >> 16);
        b16ok = b16ok && (h0 == 0u || h0 == 0x3F80u) && (h1 == 0u || h1 == 0x3F80u);
      }
      int ai = __all(i32ok ? 1 : 0), af = __all(f32ok ? 1 : 0), ab = __all(b16ok ? 1 : 0);
      ak = ai ? 0 : (af ? 1 : (ab ? 2 : 3));
    }
    if (lane == 0) { flg[0] = bfall; flg[1] = ak; }
  }
  __syncthreads();
}

// ---------------- K1: convert small weights to f32 / f16 (+ transpose W_last) ----------------
__global__ __launch_bounds__(256) void k_convert(const void* __restrict__ x,
                                                 const void* __restrict__ Wl, const void* __restrict__ al,
                                                 const void* __restrict__ Wlast,
                                                 float* __restrict__ Wlf, float* __restrict__ alf,
                                                 _Float16* __restrict__ Wt1, _Float16* __restrict__ Wt2,
                                                 float* __restrict__ wlv) {
  __shared__ int flg[2];
  detect_flags(x, nullptr, flg);
  const int isbf = flg[0];
  constexpr int NW = L_ * H_ * HD_ * HD_;  // 6144
  constexpr int NA = L_ * H_ * 2 * HD_;    // 768
  constexpr int NL = E_ * (2 * E_ + 1);    // 32896
  for (int i = blockIdx.x * 256 + threadIdx.x; i < NW + NA + NL; i += gridDim.x * 256) {
    if (i < NW) Wlf[i] = ld_f(Wl, i, isbf);
    else if (i < NW + NA) alf[i - NW] = ld_f(al, i - NW, isbf);
    else {
      int j = i - NW - NA;
      int e = j / 257, c = j - e * 257;
      float v = ld_f(Wlast, j, isbf);
      if (c < 128) Wt1[c * 128 + e] = (_Float16)v;          // Wt1[k][e] = W1[e][k]
      else if (c < 256) Wt2[(c - 128) * 128 + e] = (_Float16)v;
      else wlv[e] = v;
    }
  }
}

// ---------------- K2: all 3 GAT layers, one block per (b, head), everything in LDS ----------------
__global__ __launch_bounds__(256) void k_gat(const void* __restrict__ x, const void* __restrict__ adj,
                                             const float* __restrict__ Wlf, const float* __restrict__ alf,
                                             _Float16* __restrict__ hE) {
  __shared__ struct {
    unsigned long long maskw[U_][4];                  // adj bitmask per row
    float eu[U_], ev[V_], es[N_];
    float mU[U_], sU[U_], selfU[U_], rU[U_];
    float mV[V_], sV[V_], selfV[V_], colF[V_];
    float Wsh[256], ash[32], a12[16];
    float M;
    int flg[2];
    _Float16 E[U_ * EP];                              // logits, later P = exp(E - mU)
    _Float16 Wh[N_ * HD_];                            // Wh (f16); reused to stage next-layer h
  } s;
  const int tid = threadIdx.x;
  const int b = blockIdx.x >> 3, hh = blockIdx.x & 7;
  detect_flags(x, adj, s.flg);
  const int isbf = s.flg[0], ak = s.flg[1];

  { // pack adjacency bits for this batch (shared across heads/layers)
    const int wvp = tid >> 6, lanep = tid & 63;
    for (int r = wvp; r < U_; r += 4)
      for (int c = 0; c < 4; c++) {
        int v = c * 64 + lanep;
        bool t = (v < V_) && adj_true(adj, (long)b * (U_ * V_) + (long)r * V_ + v, ak);
        unsigned long long m = __ballot(t ? 1 : 0);
        if (lanep == 0) s.maskw[r][c] = m;
      }
  }

  // h rows live in registers: thread owns rows tid and tid+256
  float hreg[2][16];
  const int row1 = tid + 256;
  {
    const long xb = (long)b * (N_ * E_) + (long)hh * (N_ * HD_);
    #pragma unroll
    for (int k = 0; k < 16; k++) hreg[0][k] = ld_f(x, xb + (long)tid * 16 + k, isbf);
    if (row1 < N_) {
      #pragma unroll
      for (int k = 0; k < 16; k++) hreg[1][k] = ld_f(x, xb + (long)row1 * 16 + k, isbf);
    }
  }
  const int wv = tid >> 6, lane = tid & 63, lm = lane & 15, lq = lane >> 4;

  for (int l = 0; l < L_; l++) {
    __syncthreads();
    s.Wsh[tid] = Wlf[(l * 8 + hh) * 256 + tid];
    if (tid < 32) s.ash[tid] = alf[(l * 8 + hh) * 32 + tid];
    __syncthreads();
    if (tid < 16) s.a12[tid] = s.ash[tid] + s.ash[16 + tid];

    { // phase1: Wh[n][d] = sum_k h[n][k] * W[d][k]
      float wr[16];
      #pragma unroll
      for (int d = 0; d < 16; d++) {
        float a = 0.f;
        #pragma unroll
        for (int k = 0; k < 16; k++) a = fmaf(hreg[0][k], s.Wsh[d * 16 + k], a);
        wr[d] = a;
      }
      half8 p0, p1;
      #pragma unroll
      for (int j = 0; j < 8; j++) { p0[j] = (_Float16)wr[j]; p1[j] = (_Float16)wr[8 + j]; }
      *(half8*)&s.Wh[tid * 16] = p0; *(half8*)&s.Wh[tid * 16 + 8] = p1;
      if (row1 < N_) {
        #pragma unroll
        for (int d = 0; d < 16; d++) {
          float a = 0.f;
          #pragma unroll
          for (int k = 0; k < 16; k++) a = fmaf(hreg[1][k], s.Wsh[d * 16 + k], a);
          wr[d] = a;
        }
        #pragma unroll
        for (int j = 0; j < 8; j++) { p0[j] = (_Float16)wr[j]; p1[j] = (_Float16)wr[8 + j]; }
        *(half8*)&s.Wh[row1 * 16] = p0; *(half8*)&s.Wh[row1 * 16 + 8] = p1;
      }
    }
    __syncthreads();
    // phase2: eu/ev/es
    for (int n = tid; n < N_; n += 256) {
      const half8 h0 = *(const half8*)&s.Wh[n * 16];
      const half8 h1 = *(const half8*)&s.Wh[n * 16 + 8];
      float w[16];
      #pragma unroll
      for (int j = 0; j < 8; j++) { w[j] = (float)h0[j]; w[8 + j] = (float)h1[j]; }
      float da = 0.f, d12 = 0.f;
      if (n < U_) { for (int k = 0; k < 16; k++) da = fmaf(w[k], s.ash[k], da); }
      else        { for (int k = 0; k < 16; k++) da = fmaf(w[k], s.ash[16 + k], da); }
      #pragma unroll
      for (int k = 0; k < 16; k++) d12 = fmaf(w[k], s.a12[k], d12);
      if (n < U_) s.eu[n] = da; else s.ev[n - U_] = da;
      s.es[n] = leaky(d12);
    }
    __syncthreads();
    // phase3: E[u][v] = masked logits (f16)
    for (int i = tid; i < U_ * EP; i += 256) {
      int u = i / EP, v = i - u * EP;
      float val = NEGI;
      if (v < V_) {
        bool msk = (s.maskw[u][v >> 6] >> (v & 63)) & 1ull;
        if (!msk) val = leaky(s.eu[u] + s.ev[v]);
      }
      s.E[i] = (_Float16)val;
    }
    __syncthreads();
    // phase4a: column maxes (incl self), row maxes (incl self)
    for (int v = tid; v < V_; v += 256) {
      float m = s.es[U_ + v];
      for (int u = 0; u < U_; u++) m = fmaxf(m, (float)s.E[u * EP + v]);
      s.mV[v] = m;
    }
    for (int u = tid; u < U_; u += 256) {
      float m = s.es[u];
      const half8* rp = (const half8*)&s.E[u * EP];
      for (int c = 0; c < EP / 8; c++) {
        half8 h = rp[c];
        #pragma unroll
        for (int j = 0; j < 8; j++) m = fmaxf(m, (float)h[j]);
      }
      s.mU[u] = m;
    }
    __syncthreads();
    // phase4a2: global M = max_u mU  (keeps P*rU <= 1, no f16/f32 overflow)
    if (tid < 64) {
      float m = -1e30f;
      for (int u = tid; u < U_; u += 64) m = fmaxf(m, s.mU[u]);
      #pragma unroll
      for (int o = 32; o > 0; o >>= 1) m = fmaxf(m, __shfl_xor(m, o));
      if (tid == 0) s.M = m;
    }
    __syncthreads();
    // phase4b: P = exp(E - mU) in place (f16, <=1), sU, selfU, rU; colF/selfV for columns
    for (int u = tid; u < U_; u += 256) {
      const float m = s.mU[u];
      float sum = __expf(s.es[u] - m);
      s.selfU[u] = sum;
      half8* rp = (half8*)&s.E[u * EP];
      for (int c = 0; c < EP / 8; c++) {
        half8 h = rp[c]; half8 o;
        #pragma unroll
        for (int j = 0; j < 8; j++) { float p = __expf((float)h[j] - m); sum += p; o[j] = (_Float16)p; }
        rp[c] = o;
      }
      s.sU[u] = sum;
      s.rU[u] = __expf(m - s.M);
    }
    for (int v = tid; v < V_; v += 256) {
      float mv = s.mV[v];
      s.colF[v] = __expf(s.M - mv);
      s.selfV[v] = __expf(s.es[U_ + v] - mv);
    }
    __syncthreads();
    // phase4c: sV[v] = colF * sum_u P*rU + selfV
    for (int v = tid; v < V_; v += 256) {
      float sum = 0.f;
      for (int u = 0; u < U_; u++) sum = fmaf((float)s.E[u * EP + v], s.rU[u], sum);
      s.sV[v] = sum * s.colF[v] + s.selfV[v];
    }
    __syncthreads();
    // phase5: hu = P @ Wh_v  and  hv = (P^T scaled) @ Wh_u  via MFMA 16x16x32 f16
    float huv[2][4] = {}; float hvv[4][4] = {};
    {
      f32x4 accU[2] = {};
      #pragma unroll
      for (int kt = 0; kt < 7; kt++) {
        half8 bf;
        #pragma unroll
        for (int j = 0; j < 8; j++) {
          int k = kt * 32 + lq * 8 + j;
          bf[j] = (k < V_) ? s.Wh[(U_ + k) * HD_ + lm] : (_Float16)0.f;
        }
        #pragma unroll
        for (int i = 0; i < 2; i++) {
          int mt = wv + 4 * i;
          if (mt >= 7) continue;
          int m = mt * 16 + lm;
          half8 af = {};
          if (m < U_ && (kt * 32 + lq * 8) < EP)
            af = *(const half8*)&s.E[m * EP + kt * 32 + lq * 8];
          accU[i] = __builtin_amdgcn_mfma_f32_16x16x32_f16(af, bf, accU[i], 0, 0, 0);
        }
      }
      #pragma unroll
      for (int i = 0; i < 2; i++) {
        int mt = wv + 4 * i;
        if (mt >= 7) continue;
        #pragma unroll
        for (int r = 0; r < 4; r++) {
          int u = mt * 16 + lq * 4 + r;
          if (u < U_) {
            float val = (accU[i][r] + s.selfU[u] * (float)s.Wh[u * HD_ + lm]) / s.sU[u];
            huv[i][r] = elu_(val);
          }
        }
      }
      f32x4 accV[4] = {};
      #pragma unroll
      for (int kt = 0; kt < 4; kt++) {
        half8 bf;
        #pragma unroll
        for (int j = 0; j < 8; j++) {
          int u = kt * 32 + lq * 8 + j;
          bf[j] = (u < U_) ? s.Wh[u * HD_ + lm] : (_Float16)0.f;
        }
        #pragma unroll
        for (int i = 0; i < 4; i++) {
          int mt = wv + 4 * i;
          if (mt >= 13) continue;
          int v = mt * 16 + lm;
          half8 af = {};
          if (v < V_) {
            float cf = s.colF[v];
            #pragma unroll
            for (int j = 0; j < 8; j++) {
              int u = kt * 32 + lq * 8 + j;
              af[j] = (u < U_) ? (_Float16)((float)s.E[u * EP + v] * s.rU[u] * cf) : (_Float16)0.f;
            }
          }
          accV[i] = __builtin_amdgcn_mfma_f32_16x16x32_f16(af, bf, accV[i], 0, 0, 0);
        }
      }
      #pragma unroll
      for (int i = 0; i < 4; i++) {
        int mt = wv + 4 * i;
        if (mt >= 13) continue;
        #pragma unroll
        for (int r = 0; r < 4; r++) {
          int v = mt * 16 + lq * 4 + r;
          if (v < V_) {
            float val = (accV[i][r] + s.selfV[v] * (float)s.Wh[(U_ + v) * HD_ + lm]) / s.sV[v];
            hvv[i][r] = elu_(val);
          }
        }
      }
    }
    __syncthreads();
    // phase8: stage new h (into Wh buffer) or final write to global hE
    if (l < L_ - 1) {
      #pragma unroll
      for (int i = 0; i < 2; i++) {
        int mt = wv + 4 * i; if (mt >= 7) continue;
        #pragma unroll
        for (int r = 0; r < 4; r++) {
          int u = mt * 16 + lq * 4 + r;
          if (u < U_) s.Wh[u * HD_ + lm] = (_Float16)huv[i][r];
        }
      }
      #pragma unroll
      for (int i = 0; i < 4; i++) {
        int mt = wv + 4 * i; if (mt >= 13) continue;
        #pragma unroll
        for (int r = 0; r < 4; r++) {
          int v = mt * 16 + lq * 4 + r;
          if (v < V_) s.Wh[(U_ + v) * HD_ + lm] = (_Float16)hvv[i][r];
        }
      }
      __syncthreads();
      #pragma unroll
      for (int k = 0; k < 16; k++) hreg[0][k] = (float)s.Wh[tid * 16 + k];
      if (row1 < N_) {
        #pragma unroll
        for (int k = 0; k < 16; k++) hreg[1][k] = (float)s.Wh[row1 * 16 + k];
      }
    } else {
      _Float16* op = hE + (long)b * (N_ * E_) + (long)hh * (N_ * HD_);
      #pragma unroll
      for (int i = 0; i < 2; i++) {
        int mt = wv + 4 * i; if (mt >= 7) continue;
        #pragma unroll
        for (int r = 0; r < 4; r++) {
          int u = mt * 16 + lq * 4 + r;
          if (u < U_) op[u * HD_ + lm] = (_Float16)huv[i][r];
        }
      }
      #pragma unroll
      for (int i = 0; i < 4; i++) {
        int mt = wv + 4 * i; if (mt >= 13) continue;
        #pragma unroll
        for (int r = 0; r < 4; r++) {
          int v = mt * 16 + lq * 4 + r;
          if (v < V_) op[(U_ + v) * HD_ + lm] = (_Float16)hvv[i][r];
        }
      }
    }
  }
}

// ---------------- K3: pu = hE[:U] @ W1^T, pv = hE[U:] @ W2^T  (MFMA) ----------------
__global__ __launch_bounds__(256) void k_pupv(const _Float16* __restrict__ hE,
                                              const _Float16* __restrict__ Wt1,
                                              const _Float16* __restrict__ Wt2,
                                              float* __restrict__ pu, float* __restrict__ pv) {
  __shared__ _Float16 At[16 * 136];
  __shared__ _Float16 Bt[128 * 136];
  const int tid = threadIdx.x;
  const int b = blockIdx.x / 20, t = blockIdx.x % 20;
  const bool isU = t < 7;
  const int r0 = (isU ? t : t - 7) * 16;
  const int rows = isU ? U_ : V_;
  const int base = isU ? 0 : U_;
  const _Float16* W = isU ? Wt1 : Wt2;
  {
    int rr = tid >> 4, c8 = (tid & 15) * 8;
    half8 v = {};
    if (r0 + rr < rows) v = *(const half8*)&hE[(long)b * (N_ * E_) + (long)(base + r0 + rr) * E_ + c8];
    *(half8*)&At[rr * 136 + c8] = v;
  }
  for (int i = tid; i < 128 * 16; i += 256) {
    int k = i >> 4, c8 = (i & 15) * 8;
    *(half8*)&Bt[k * 136 + c8] = *(const half8*)&W[k * 128 + c8];
  }
  __syncthreads();
  const int wv = tid >> 6, lane = tid & 63, lm = lane & 15, lq = lane >> 4;
  f32x4 acc[2] = {};
  #pragma unroll
  for (int kt = 0; kt < 4; kt++) {
    half8 af = *(const half8*)&At[lm * 136 + kt * 32 + lq * 8];
    #pragma unroll
    for (int i = 0; i < 2; i++) {
      int nt = wv + 4 * i;
      int n = nt * 16 + lm;
      half8 bf;
      #pragma unroll
      for (int j = 0; j < 8; j++) bf[j] = Bt[(kt * 32 + lq * 8 + j) * 136 + n];
      acc[i] = __builtin_amdgcn_mfma_f32_16x16x32_f16(af, bf, acc[i], 0, 0, 0);
    }
  }
  float* out = isU ? pu : pv;
  #pragma unroll
  for (int i = 0; i < 2; i++) {
    int nt = wv + 4 * i;
    #pragma unroll
    for (int r = 0; r < 4; r++) {
      int grow = r0 + lq * 4 + r;
      if (grow < rows) out[(long)b * rows * E_ + (long)grow * E_ + nt * 16 + lm] = acc[i][r];
    }
  }
}

// ---------------- K4: out[b,u,v,:] = mask*(pu+pv) + weights*wl  (write-bound) ----------------
__global__ __launch_bounds__(256) void k_out(const void* __restrict__ x, const void* __restrict__ adj,
                                             const void* __restrict__ wgt,
                                             const float* __restrict__ pu, const float* __restrict__ pv,
                                             const float* __restrict__ wlv, void* __restrict__ out) {
  __shared__ int flg[2];
  __shared__ float puS[128], wlS[128];
  detect_flags(x, adj, flg);
  const int isbf = flg[0], ak = flg[1];
  const int tid = threadIdx.x;
  const int b = blockIdx.x / U_, u = blockIdx.x % U_;
  if (tid < 128) {
    puS[tid] = pu[((long)b * U_ + u) * E_ + tid];
    wlS[tid] = wlv[tid];
  }
  __syncthreads();
  const int ei = (tid & 15) * 8;
  float p8[8], w8[8];
  #pragma unroll
  for (int j = 0; j < 8; j++) { p8[j] = puS[ei + j]; w8[j] = wlS[ei + j]; }
  for (int v = tid >> 4; v < V_; v += 16) {
    const long mi = (long)b * (U_ * V_) + (long)u * V_ + v;
    const float msk = adj_true(adj, mi, ak) ? 0.f : 1.f;
    const float wq = ld_f(wgt, mi, isbf);
    const float4* pvp = (const float4*)&pv[((long)b * V_ + v) * E_ + ei];
    float4 a = pvp[0], c = pvp[1];
    float o[8];
    o[0] = msk * (p8[0] + a.x) + wq * w8[0];
    o[1] = msk * (p8[1] + a.y) + wq * w8[1];
    o[2] = msk * (p8[2] + a.z) + wq * w8[2];
    o[3] = msk * (p8[3] + a.w) + wq * w8[3];
    o[4] = msk * (p8[4] + c.x) + wq * w8[4];
    o[5] = msk * (p8[5] + c.y) + wq * w8[5];
    o[6] = msk * (p8[6] + c.z) + wq * w8[6];
    o[7] = msk * (p8[7] + c.w) + wq * w8[7];
    const long ob = ((long)b * (U_ * V_) + (long)u * V_ + v) * E_ + ei;
    if (isbf) {
      uint4 pk;
      pk.x = (unsigned)f2bf(o[0]) | ((unsigned)f2bf(o[1]) << 16);
      pk.y = (unsigned)f2bf(o[2]) | ((unsigned)f2bf(o[3]) << 16);
      pk.z = (unsigned)f2bf(o[4]) | ((unsigned)f2bf(o[5]) << 16);
      pk.w = (unsigned)f2bf(o[6]) | ((unsigned)f2bf(o[7]) << 16);
      *(uint4*)((unsigned short*)out + ob) = pk;
    } else {
      float* op = (float*)out + ob;
      float4 f0 = {o[0], o[1], o[2], o[3]}, f1 = {o[4], o[5], o[6], o[7]};
      *(float4*)op = f0;
      *(float4*)(op + 4) = f1;
    }
  }
}

extern "C" void kernel_launch(void* const* d_in, const int* in_sizes, int n_in,
                              void* d_out, int out_size, void* d_ws, size_t ws_size,
                              hipStream_t stream) {
  const void* x     = d_in[0];
  const void* adj   = d_in[1];
  const void* wgt   = d_in[2];
  const void* Wl    = d_in[3];
  const void* al    = d_in[4];
  const void* Wlast = d_in[5];

  char* ws = (char*)d_ws;
  size_t off = 0;
  auto alloc = [&](size_t bytes) -> void* {
    void* p = ws + off;
    off += (bytes + 255) & ~(size_t)255;
    return p;
  };
  float*     Wlf = (float*)alloc(6144 * 4);
  float*     alf = (float*)alloc(768 * 4);
  _Float16*  Wt1 = (_Float16*)alloc(16384 * 2);
  _Float16*  Wt2 = (_Float16*)alloc(16384 * 2);
  float*     wlv = (float*)alloc(128 * 4);
  _Float16*  hE  = (_Float16*)alloc((size_t)B_ * N_ * E_ * 2);
  float*     pu  = (float*)alloc((size_t)B_ * U_ * E_ * 4);
  float*     pv  = (float*)alloc((size_t)B_ * V_ * E_ * 4);

  k_convert<<<156, 256, 0, stream>>>(x, Wl, al, Wlast, Wlf, alf, Wt1, Wt2, wlv);
  k_gat<<<B_ * H_, 256, 0, stream>>>(x, adj, Wlf, alf, hE);
  k_pupv<<<B_ * 20, 256, 0, stream>>>(hE, Wt1, Wt2, pu, pv);
  k_out<<<B_ * U_, 256, 0, stream>>>(x, adj, wgt, pu, pv, wlv, d_out);
}

// Round 5
// 277.159 us; speedup vs baseline: 1.2483x; 1.2483x over previous
//
#include <hip/hip_runtime.h>
#include <hip/hip_bf16.h>

#define DI __device__ __forceinline__

typedef _Float16 half8 __attribute__((ext_vector_type(8)));
typedef float f32x4 __attribute__((ext_vector_type(4)));

constexpr int B_ = 16, H_ = 8, N_ = 300, U_ = 100, V_ = 200, HD_ = 16, E_ = 128, L_ = 3;
constexpr float ALPHA_ = 0.01f;

DI float leaky(float x) { return x > 0.f ? x : ALPHA_ * x; }
DI float elu_(float x)  { return x > 0.f ? x : __expf(x) - 1.f; }

DI unsigned short f2bf(float f) {   // RNE f32->bf16
  unsigned u = __float_as_uint(f);
  unsigned r = (u + 0x7FFFu + ((u >> 16) & 1u)) >> 16;
  return (unsigned short)r;
}
DI float ld_f(const void* p, long i, int isbf) {
  if (isbf) return __uint_as_float(((unsigned)((const unsigned short*)p)[i]) << 16);
  return ((const float*)p)[i];
}
DI bool adj_true(const void* a, long i, int k) {
  switch (k) {
    case 0:  return ((const int*)a)[i] != 0;
    case 1:  return ((const float*)a)[i] != 0.f;
    case 2:  return ((const unsigned short*)a)[i] != 0;
    default: return ((const unsigned char*)a)[i] != 0;
  }
}

// Runtime input-format detection (wave 0 scans leading bytes; flg[0]=float-is-bf16, flg[1]=adj kind)
DI void detect_flags(const void* x, const void* adj, int* flg) {
  if (threadIdx.x < 64) {
    int lane = threadIdx.x;
    const unsigned short* xh = (const unsigned short*)x;
    bool okbf = true;
    #pragma unroll
    for (int i = 0; i < 16; i++) {
      float f = __uint_as_float(((unsigned)xh[lane * 16 + i]) << 16);
      okbf = okbf && (f == f) && (fabsf(f) < 1e6f);
    }
    int bfall = __all(okbf ? 1 : 0);
    int ak = 3;
    if (adj) {
      const unsigned* aw = (const unsigned*)adj;
      bool i32ok = true, f32ok = true, b16ok = true;
      #pragma unroll
      for (int i = 0; i < 16; i++) {
        unsigned w = aw[lane * 16 + i];
        i32ok = i32ok && (w == 0u || w == 1u);
        f32ok = f32ok && (w == 0u || w == 0x3F800000u);
        unsigned short h0 = (unsigned short)(w & 0xFFFFu), h1 = (unsigned short)(w >> 16);
        b16ok = b16ok && (h0 == 0u || h0 == 0x3F80u) && (h1 == 0u || h1 == 0x3F80u);
      }
      int ai = __all(i32ok ? 1 : 0), af = __all(f32ok ? 1 : 0), ab = __all(b16ok ? 1 : 0);
      ak = ai ? 0 : (af ? 1 : (ab ? 2 : 3));
    }
    if (lane == 0) { flg[0] = bfall; flg[1] = ak; }
  }
  __syncthreads();
}

// ---------------- K1: convert weights (W layers -> f16; W_last -> f16 transposed) ----------------
__global__ __launch_bounds__(256) void k_convert(const void* __restrict__ x,
                                                 const void* __restrict__ Wl, const void* __restrict__ al,
                                                 const void* __restrict__ Wlast,
                                                 _Float16* __restrict__ Wlf16, float* __restrict__ alf,
                                                 _Float16* __restrict__ Wt1, _Float16* __restrict__ Wt2,
                                                 float* __restrict__ wlv) {
  __shared__ int flg[2];
  detect_flags(x, nullptr, flg);
  const int isbf = flg[0];
  constexpr int NW = L_ * H_ * HD_ * HD_;  // 6144
  constexpr int NA = L_ * H_ * 2 * HD_;    // 768
  constexpr int NL = E_ * (2 * E_ + 1);    // 32896
  for (int i = blockIdx.x * 256 + threadIdx.x; i < NW + NA + NL; i += gridDim.x * 256) {
    if (i < NW) Wlf16[i] = (_Float16)ld_f(Wl, i, isbf);
    else if (i < NW + NA) alf[i - NW] = ld_f(al, i - NW, isbf);
    else {
      int j = i - NW - NA;
      int e = j / 257, c = j - e * 257;
      float v = ld_f(Wlast, j, isbf);
      if (c < 128) Wt1[c * 128 + e] = (_Float16)v;
      else if (c < 256) Wt2[(c - 128) * 128 + e] = (_Float16)v;
      else wlv[e] = v;
    }
  }
}

// ---------------- K2: all 3 GAT layers, flash-style (no E matrix), 512 thr / (b,head) ----------------
// NOTE: resubmit of round-4 source after hand-audit (all LDS/global accesses bounds- and
// alignment-verified; suspected infra/HSA flake, not a code defect).
__global__ __launch_bounds__(512) void k_gat(const void* __restrict__ x, const void* __restrict__ adj,
                                             const _Float16* __restrict__ Wlf16, const float* __restrict__ alf,
                                             _Float16* __restrict__ hE) {
  __shared__ struct {
    unsigned long long maskw[112][4];   // row bitmask over v (bit=1 => excluded); rows>=100 all 1
    unsigned long long maskv[208][2];   // col bitmask over u (bit=1 => excluded); cols>=200 all 1
    __attribute__((aligned(16))) _Float16 hS[304][16];   // current layer input h
    __attribute__((aligned(16))) _Float16 Wh[304][16];   // Wh row-major (self terms)
    __attribute__((aligned(16))) _Float16 WhT[16][328];  // Wh transposed: u at col (0..99), v at col+104 (104..303)
                                                         // cols 100..103 / 304..327 are zero pad (read by masked MFMA)
    __attribute__((aligned(16))) float eu[128];
    __attribute__((aligned(16))) float ev[256];
    __attribute__((aligned(16))) float es[312];
    float mEU, mEV;
    int flg[2];
  } s;
  const int tid = threadIdx.x;
  const int b = blockIdx.x >> 3, hh = blockIdx.x & 7;
  detect_flags(x, adj, s.flg);
  const int isbf = s.flg[0], ak = s.flg[1];
  const int wv = tid >> 6, lane = tid & 63, lm = lane & 15, lq = lane >> 4;
  const long adjb = (long)b * (U_ * V_);

  // ---- prologue: pack masks, zero pads, load h0 ----
  for (int r = wv; r < 112; r += 8) {
    #pragma unroll
    for (int c = 0; c < 4; c++) {
      int v = c * 64 + lane;
      bool ex = true;
      if (r < U_ && v < V_) ex = adj_true(adj, adjb + (long)r * V_ + v, ak);
      unsigned long long m = __ballot(ex ? 1 : 0);
      if (lane == 0) s.maskw[r][c] = m;
    }
  }
  for (int v = wv; v < 208; v += 8) {
    bool e0 = true, e1 = true;
    if (v < V_) {
      e0 = adj_true(adj, adjb + (long)lane * V_ + v, ak);
      int u1 = 64 + lane;
      if (u1 < U_) e1 = adj_true(adj, adjb + (long)u1 * V_ + v, ak);
    }
    unsigned long long m0 = __ballot(e0 ? 1 : 0);
    unsigned long long m1 = __ballot(e1 ? 1 : 0);
    if (lane == 0) { s.maskv[v][0] = m0; s.maskv[v][1] = m1; }
  }
  // zero WhT entirely (data cols rewritten each layer; pad cols must be 0, NaN-free for masked MFMA reads)
  for (int i = tid; i < 16 * 328 / 2; i += 512) ((unsigned*)&s.WhT[0][0])[i] = 0u;
  // zero pads
  if (tid < 28) s.eu[100 + tid] = 0.f;
  if (tid >= 32 && tid < 88) s.ev[200 + (tid - 32)] = 0.f;
  if (tid >= 96 && tid < 108) s.es[300 + (tid - 96)] = 0.f;
  if (tid >= 128 && tid < 160) ((unsigned*)&s.hS[300][0])[tid - 128] = 0u;  // rows 300..303 (64 halves = 32 uints)
  // load h0 (layer-0 input) rows
  if (tid < N_) {
    const long xb = (long)b * (N_ * E_) + (long)hh * (N_ * HD_) + (long)tid * 16;
    half8 p0, p1;
    #pragma unroll
    for (int k = 0; k < 8; k++) { p0[k] = (_Float16)ld_f(x, xb + k, isbf); p1[k] = (_Float16)ld_f(x, xb + 8 + k, isbf); }
    *(half8*)&s.hS[tid][0] = p0; *(half8*)&s.hS[tid][8] = p1;
  }
  __syncthreads();

  half8 ones8;
  #pragma unroll
  for (int j = 0; j < 8; j++) ones8[j] = (_Float16)1.f;

  for (int l = 0; l < L_; l++) {
    // ---- phase1: Wh = h @ W^T via MFMA 16x16x32 (K zero-padded 16->32); eu/ev/es via shuffles ----
    {
      const int base32 = (l * 8 + hh) * 32;
      const float a1l = alf[base32 + lm], a2l = alf[base32 + 16 + lm];
      half8 bW = {};
      if (lq < 2) bW = *(const half8*)&Wlf16[(l * 8 + hh) * 256 + lm * 16 + lq * 8];  // B[k][d]=W[d][k], k<16
      for (int t = wv; t < 19; t += 8) {
        const int row_a = t * 16 + lm;
        half8 af = {};
        if (lq < 2) af = *(const half8*)&s.hS[row_a][lq * 8];
        f32x4 z = {0.f, 0.f, 0.f, 0.f};
        f32x4 dW = __builtin_amdgcn_mfma_f32_16x16x32_f16(af, bW, z, 0, 0, 0);
        #pragma unroll
        for (int r = 0; r < 4; r++) {
          const int row = t * 16 + lq * 4 + r;
          const float aX = (row < U_) ? a1l : a2l;
          float d1 = dW[r] * aX, d2 = dW[r] * (a1l + a2l);
          #pragma unroll
          for (int o = 1; o < 16; o <<= 1) { d1 += __shfl_xor(d1, o); d2 += __shfl_xor(d2, o); }
          if (row < N_) {
            s.Wh[row][lm] = (_Float16)dW[r];
            s.WhT[lm][row < U_ ? row : row + 4] = (_Float16)dW[r];
            if (lm == 0) { if (row < U_) s.eu[row] = d1; else s.ev[row - U_] = d1; }
            if (lm == 1) s.es[row] = leaky(d2);
          }
        }
      }
    }
    __syncthreads();
    // ---- global maxes mEU, mEV ----
    if (wv == 0) {
      float m = fmaxf(s.eu[lane], s.eu[64 + lane]);
      #pragma unroll
      for (int o = 32; o > 0; o >>= 1) m = fmaxf(m, __shfl_xor(m, o));
      if (lane == 0) s.mEU = m;
    } else if (wv == 1) {
      float m = fmaxf(fmaxf(s.ev[lane], s.ev[64 + lane]), fmaxf(s.ev[128 + lane], s.ev[192 + lane]));
      #pragma unroll
      for (int o = 32; o > 0; o >>= 1) m = fmaxf(m, __shfl_xor(m, o));
      if (lane == 0) s.mEV = m;
    }
    __syncthreads();
    const float mEU = s.mEU, mEV = s.mEV;
    const bool last = (l == L_ - 1);
    _Float16* outp = hE + (long)b * (N_ * E_) + (long)hh * (N_ * HD_);

    // ---- phase5-U: hu rows, tiles 0..6 (wave w -> tile w) ----
    if (wv < 7) {
      const int t = wv;
      const int u_a = t * 16 + lm;
      const float eu_a = s.eu[u_a];
      const float sh_a = fmaxf(fmaxf(eu_a + mEV, 0.f), s.es[u_a]);
      const unsigned long long mw0 = s.maskw[u_a][0], mw1 = s.maskw[u_a][1];
      const unsigned long long mw2 = s.maskw[u_a][2], mw3 = s.maskw[u_a][3];
      f32x4 accU = {0.f, 0.f, 0.f, 0.f}, accS = {0.f, 0.f, 0.f, 0.f};
      #pragma unroll
      for (int kt = 0; kt < 7; kt++) {
        const int base = kt * 32 + lq * 8;
        unsigned long long w = (base < 64) ? mw0 : (base < 128) ? mw1 : (base < 192) ? mw2 : mw3;
        const unsigned bits = (unsigned)(w >> (base & 63)) & 0xFFu;
        const float4 e0 = *(const float4*)&s.ev[base];
        const float4 e1 = *(const float4*)&s.ev[base + 4];
        const float ev8[8] = {e0.x, e0.y, e0.z, e0.w, e1.x, e1.y, e1.z, e1.w};
        half8 af;
        #pragma unroll
        for (int j = 0; j < 8; j++) {
          float p = __expf(leaky(eu_a + ev8[j]) - sh_a);
          af[j] = (bits >> j & 1u) ? (_Float16)0.f : (_Float16)p;
        }
        const half8 bf = *(const half8*)&s.WhT[lm][104 + base];
        accU = __builtin_amdgcn_mfma_f32_16x16x32_f16(af, bf, accU, 0, 0, 0);
        accS = __builtin_amdgcn_mfma_f32_16x16x32_f16(af, ones8, accS, 0, 0, 0);
      }
      #pragma unroll
      for (int r = 0; r < 4; r++) {
        const int u_c = t * 16 + lq * 4 + r;
        if (u_c < U_) {
          const float eu_c = s.eu[u_c];
          const float sh_c = fmaxf(fmaxf(eu_c + mEV, 0.f), s.es[u_c]);
          const float self = __expf(s.es[u_c] - sh_c);
          const float num = accU[r] + self * (float)s.Wh[u_c][lm];
          const float den = accS[r] + self;
          const float o = elu_(num / den);
          if (last) outp[u_c * 16 + lm] = (_Float16)o;
          else s.hS[u_c][lm] = (_Float16)o;
        }
      }
    }
    // ---- phase5-V: hv rows, 13 tiles distributed over 8 waves ----
    {
      int vt0 = wv, vt1 = -1, vt2 = -1;
      if (wv == 4) vt1 = 12;
      else if (wv == 5) vt1 = 10;
      else if (wv == 6) vt1 = 11;
      else if (wv == 7) { vt1 = 8; vt2 = 9; }
      const int vts[3] = {vt0, vt1, vt2};
      #pragma unroll
      for (int ti = 0; ti < 3; ti++) {
        const int t = vts[ti];
        if (t < 0) continue;
        const int v_a = t * 16 + lm;
        const float ev_a = s.ev[v_a];
        const float sh_a = fmaxf(fmaxf(ev_a + mEU, 0.f), s.es[U_ + v_a]);
        const unsigned long long m0 = s.maskv[v_a][0], m1 = s.maskv[v_a][1];
        f32x4 accV = {0.f, 0.f, 0.f, 0.f}, accS = {0.f, 0.f, 0.f, 0.f};
        #pragma unroll
        for (int kt = 0; kt < 4; kt++) {
          const int base = kt * 32 + lq * 8;
          const unsigned bits = (unsigned)(((base < 64) ? m0 : m1) >> (base & 63)) & 0xFFu;
          const float4 u0 = *(const float4*)&s.eu[base];
          const float4 u1 = *(const float4*)&s.eu[base + 4];
          const float eu8[8] = {u0.x, u0.y, u0.z, u0.w, u1.x, u1.y, u1.z, u1.w};
          half8 af;
          #pragma unroll
          for (int j = 0; j < 8; j++) {
            float p = __expf(leaky(eu8[j] + ev_a) - sh_a);
            af[j] = (bits >> j & 1u) ? (_Float16)0.f : (_Float16)p;
          }
          const half8 bf = *(const half8*)&s.WhT[lm][base];
          accV = __builtin_amdgcn_mfma_f32_16x16x32_f16(af, bf, accV, 0, 0, 0);
          accS = __builtin_amdgcn_mfma_f32_16x16x32_f16(af, ones8, accS, 0, 0, 0);
        }
        #pragma unroll
        for (int r = 0; r < 4; r++) {
          const int v_c = t * 16 + lq * 4 + r;
          if (v_c < V_) {
            const float ev_c = s.ev[v_c];
            const float sh_c = fmaxf(fmaxf(ev_c + mEU, 0.f), s.es[U_ + v_c]);
            const float self = __expf(s.es[U_ + v_c] - sh_c);
            const float num = accV[r] + self * (float)s.Wh[U_ + v_c][lm];
            const float den = accS[r] + self;
            const float o = elu_(num / den);
            if (last) outp[(U_ + v_c) * 16 + lm] = (_Float16)o;
            else s.hS[U_ + v_c][lm] = (_Float16)o;
          }
        }
      }
    }
    __syncthreads();
  }
}

// ---------------- K3: pu = hE[:U] @ W1^T, pv = hE[U:] @ W2^T  (MFMA) ----------------
__global__ __launch_bounds__(256) void k_pupv(const _Float16* __restrict__ hE,
                                              const _Float16* __restrict__ Wt1,
                                              const _Float16* __restrict__ Wt2,
                                              float* __restrict__ pu, float* __restrict__ pv) {
  __shared__ _Float16 At[16 * 136];
  __shared__ _Float16 Bt[128 * 136];
  const int tid = threadIdx.x;
  const int b = blockIdx.x / 20, t = blockIdx.x % 20;
  const bool isU = t < 7;
  const int r0 = (isU ? t : t - 7) * 16;
  const int rows = isU ? U_ : V_;
  const int base = isU ? 0 : U_;
  const _Float16* W = isU ? Wt1 : Wt2;
  {
    int rr = tid >> 4, c8 = (tid & 15) * 8;
    half8 v = {};
    if (r0 + rr < rows) v = *(const half8*)&hE[(long)b * (N_ * E_) + (long)(base + r0 + rr) * E_ + c8];
    *(half8*)&At[rr * 136 + c8] = v;
  }
  for (int i = tid; i < 128 * 16; i += 256) {
    int k = i >> 4, c8 = (i & 15) * 8;
    *(half8*)&Bt[k * 136 + c8] = *(const half8*)&W[k * 128 + c8];
  }
  __syncthreads();
  const int wv = tid >> 6, lane = tid & 63, lm = lane & 15, lq = lane >> 4;
  f32x4 acc[2] = {};
  #pragma unroll
  for (int kt = 0; kt < 4; kt++) {
    half8 af = *(const half8*)&At[lm * 136 + kt * 32 + lq * 8];
    #pragma unroll
    for (int i = 0; i < 2; i++) {
      int nt = wv + 4 * i;
      int n = nt * 16 + lm;
      half8 bf;
      #pragma unroll
      for (int j = 0; j < 8; j++) bf[j] = Bt[(kt * 32 + lq * 8 + j) * 136 + n];
      acc[i] = __builtin_amdgcn_mfma_f32_16x16x32_f16(af, bf, acc[i], 0, 0, 0);
    }
  }
  float* out = isU ? pu : pv;
  #pragma unroll
  for (int i = 0; i < 2; i++) {
    int nt = wv + 4 * i;
    #pragma unroll
    for (int r = 0; r < 4; r++) {
      int grow = r0 + lq * 4 + r;
      if (grow < rows) out[(long)b * rows * E_ + (long)grow * E_ + nt * 16 + lm] = acc[i][r];
    }
  }
}

// ---------------- K4: out[b,u,v,:] = mask*(pu+pv) + weights*wl  (write-bound) ----------------
__global__ __launch_bounds__(256) void k_out(const void* __restrict__ x, const void* __restrict__ adj,
                                             const void* __restrict__ wgt,
                                             const float* __restrict__ pu, const float* __restrict__ pv,
                                             const float* __restrict__ wlv, void* __restrict__ out) {
  __shared__ int flg[2];
  __shared__ float puS[128], wlS[128];
  detect_flags(x, adj, flg);
  const int isbf = flg[0], ak = flg[1];
  const int tid = threadIdx.x;
  const int b = blockIdx.x / U_, u = blockIdx.x % U_;
  if (tid < 128) {
    puS[tid] = pu[((long)b * U_ + u) * E_ + tid];
    wlS[tid] = wlv[tid];
  }
  __syncthreads();
  const int ei = (tid & 15) * 8;
  float p8[8], w8[8];
  #pragma unroll
  for (int j = 0; j < 8; j++) { p8[j] = puS[ei + j]; w8[j] = wlS[ei + j]; }
  for (int v = tid >> 4; v < V_; v += 16) {
    const long mi = (long)b * (U_ * V_) + (long)u * V_ + v;
    const float msk = adj_true(adj, mi, ak) ? 0.f : 1.f;
    const float wq = ld_f(wgt, mi, isbf);
    const float4* pvp = (const float4*)&pv[((long)b * V_ + v) * E_ + ei];
    float4 a = pvp[0], c = pvp[1];
    float o[8];
    o[0] = msk * (p8[0] + a.x) + wq * w8[0];
    o[1] = msk * (p8[1] + a.y) + wq * w8[1];
    o[2] = msk * (p8[2] + a.z) + wq * w8[2];
    o[3] = msk * (p8[3] + a.w) + wq * w8[3];
    o[4] = msk * (p8[4] + c.x) + wq * w8[4];
    o[5] = msk * (p8[5] + c.y) + wq * w8[5];
    o[6] = msk * (p8[6] + c.z) + wq * w8[6];
    o[7] = msk * (p8[7] + c.w) + wq * w8[7];
    const long ob = ((long)b * (U_ * V_) + (long)u * V_ + v) * E_ + ei;
    if (isbf) {
      uint4 pk;
      pk.x = (unsigned)f2bf(o[0]) | ((unsigned)f2bf(o[1]) << 16);
      pk.y = (unsigned)f2bf(o[2]) | ((unsigned)f2bf(o[3]) << 16);
      pk.z = (unsigned)f2bf(o[4]) | ((unsigned)f2bf(o[5]) << 16);
      pk.w = (unsigned)f2bf(o[6]) | ((unsigned)f2bf(o[7]) << 16);
      *(uint4*)((unsigned short*)out + ob) = pk;
    } else {
      float* op = (float*)out + ob;
      float4 f0 = {o[0], o[1], o[2], o[3]}, f1 = {o[4], o[5], o[6], o[7]};
      *(float4*)op = f0;
      *(float4*)(op + 4) = f1;
    }
  }
}

extern "C" void kernel_launch(void* const* d_in, const int* in_sizes, int n_in,
                              void* d_out, int out_size, void* d_ws, size_t ws_size,
                              hipStream_t stream) {
  const void* x     = d_in[0];
  const void* adj   = d_in[1];
  const void* wgt   = d_in[2];
  const void* Wl    = d_in[3];
  const void* al    = d_in[4];
  const void* Wlast = d_in[5];

  char* ws = (char*)d_ws;
  size_t off = 0;
  auto alloc = [&](size_t bytes) -> void* {
    void* p = ws + off;
    off += (bytes + 255) & ~(size_t)255;
    return p;
  };
  _Float16*  Wlf16 = (_Float16*)alloc(6144 * 2);
  float*     alf   = (float*)alloc(768 * 4);
  _Float16*  Wt1   = (_Float16*)alloc(16384 * 2);
  _Float16*  Wt2   = (_Float16*)alloc(16384 * 2);
  float*     wlv   = (float*)alloc(128 * 4);
  _Float16*  hE    = (_Float16*)alloc((size_t)B_ * N_ * E_ * 2);
  float*     pu    = (float*)alloc((size_t)B_ * U_ * E_ * 4);
  float*     pv    = (float*)alloc((size_t)B_ * V_ * E_ * 4);

  k_convert<<<156, 256, 0, stream>>>(x, Wl, al, Wlast, Wlf16, alf, Wt1, Wt2, wlv);
  k_gat<<<B_ * H_, 512, 0, stream>>>(x, adj, Wlf16, alf, hE);
  k_pupv<<<B_ * 20, 256, 0, stream>>>(hE, Wt1, Wt2, pu, pv);
  k_out<<<B_ * U_, 256, 0, stream>>>(x, adj, wgt, pu, pv, wlv, d_out);
}